// Round 15
// baseline (972.190 us; speedup 1.0000x reference)
//
#include <hip/hip_runtime.h>

// ---------------------------------------------------------------------------
// TransformerEncoder on MI355X (gfx950).
// B=8 S=1024 IN=64 D=512 F=2048 H=8 HD=64 L=6. All inputs fp32, output fp32.
// R15: attn XCD map co-locates all 8 q-blocks of a (b,h) on one XCD
//      (K/V 2MB/XCD -> L2-resident; FETCH was 69.7MB vs 25MB unique);
//      f2bf -> native __bf16 cast (HW cvt, pairs fuse to v_cvt_pk_bf16_f32).
// ---------------------------------------------------------------------------

typedef unsigned short u16;
typedef __attribute__((ext_vector_type(8))) __bf16 bf16x8;
typedef __attribute__((ext_vector_type(2))) __bf16 bf16x2;
typedef __attribute__((ext_vector_type(4))) float f32x4;
typedef __attribute__((ext_vector_type(16))) float f32x16;
typedef __attribute__((ext_vector_type(8))) unsigned short u16x8;

#define DEV __device__ __forceinline__

DEV u16 f2bf(float f) {               // native RNE cast (HW v_cvt)
  __bf16 h = (__bf16)f;
  return __builtin_bit_cast(u16, h);
}
DEV float bf2f(u16 h) { return __builtin_bit_cast(float, ((unsigned)h) << 16); }
DEV unsigned pk2(float a, float b) {  // pack 2 floats -> 2 bf16 (cvt_pk)
  bf16x2 v; v[0] = (__bf16)a; v[1] = (__bf16)b;
  return __builtin_bit_cast(unsigned, v);
}

DEV void gload16(const void* g, void* l) {
  __builtin_amdgcn_global_load_lds(
      (__attribute__((address_space(1))) void*)g,
      (__attribute__((address_space(3))) void*)l, 16, 0, 0);
}

// XCD chunked swizzle: XCD owns contiguous by-strip, all bx.
DEV void xcd_map(int& bx, int& by) {
  const int nx = gridDim.x, ny = gridDim.y;
  const int orig = by * nx + bx;
  const int cpx = (nx * ny) >> 3;
  const int swz = (orig & 7) * cpx + (orig >> 3);
  by = swz / nx; bx = swz - by * nx;
}

// ---------------------------------------------------------------------------
// Batched weight transpose fp32 [K][N] -> bf16 [N][K], all weights, all layers.
// ---------------------------------------------------------------------------
__global__ __launch_bounds__(256) void transpose_all_kernel(
    const float* __restrict__ Wq, const float* __restrict__ Wk,
    const float* __restrict__ Wv, const float* __restrict__ Wo,
    const float* __restrict__ Wg, const float* __restrict__ Wu,
    const float* __restrict__ Wd,
    u16* __restrict__ WqkvT, u16* __restrict__ WoT, u16* __restrict__ WgT,
    u16* __restrict__ WuT, u16* __restrict__ WdT)
{
  const int l = blockIdx.y;
  const int idx = blockIdx.x;
  const float* src; u16* dst; int N, bx, by;
  if (idx < 1024) {
    const int w = idx >> 8, t = idx & 255;
    bx = t & 15; by = t >> 4; N = 512;
    const size_t lo = (size_t)l * 262144;
    if (w == 0)      { src = Wq + lo; dst = WqkvT + (size_t)l * 786432; }
    else if (w == 1) { src = Wk + lo; dst = WqkvT + (size_t)l * 786432 + 262144; }
    else if (w == 2) { src = Wv + lo; dst = WqkvT + (size_t)l * 786432 + 524288; }
    else             { src = Wo + lo; dst = WoT + lo; }
  } else if (idx < 2048) {
    const int t = idx - 1024; bx = t & 63; by = t >> 6; N = 2048;
    src = Wg + (size_t)l * 1048576; dst = WgT + (size_t)l * 1048576;
  } else if (idx < 3072) {
    const int t = idx - 2048; bx = t & 63; by = t >> 6; N = 2048;
    src = Wu + (size_t)l * 1048576; dst = WuT + (size_t)l * 1048576;
  } else {
    const int t = idx - 3072; bx = t & 15; by = t >> 4; N = 512;
    src = Wd + (size_t)l * 1048576; dst = WdT + (size_t)l * 1048576;
  }
  const int K = (idx >= 3072) ? 2048 : 512;
  __shared__ float tl[32][33];
  const int n0 = bx * 32, k0 = by * 32;
  const int tx = threadIdx.x & 31, ty = threadIdx.x >> 5;
#pragma unroll
  for (int i = 0; i < 4; ++i)
    tl[ty + i * 8][tx] = src[(size_t)(k0 + ty + i * 8) * N + n0 + tx];
  __syncthreads();
#pragma unroll
  for (int i = 0; i < 4; ++i)
    dst[(size_t)(n0 + ty + i * 8) * K + k0 + tx] = f2bf(tl[tx][ty + i * 8]);
}

// pack bq|bk|bv into [L][1536]
__global__ void biaspack_kernel(const float* __restrict__ bq,
                                const float* __restrict__ bk,
                                const float* __restrict__ bv,
                                float* __restrict__ out)
{
  const int l = blockIdx.x;
  for (int c = threadIdx.x; c < 1536; c += 256) {
    float v = (c < 512) ? bq[l * 512 + c]
            : (c < 1024) ? bk[l * 512 + c - 512]
                         : bv[l * 512 + c - 1024];
    out[l * 1536 + c] = v;
  }
}

// ---------------------------------------------------------------------------
// Input adapter: x = src @ in_w + in_b + sinusoidal_pe   (fp32, [8192][512])
// ---------------------------------------------------------------------------
__global__ __launch_bounds__(256) void adapter_kernel(
    const float* __restrict__ src, const float* __restrict__ w,
    const float* __restrict__ bias, float* __restrict__ x)
{
  __shared__ float srow[8][64];
  const int m0 = blockIdx.y * 8;
  const int n = blockIdx.x * 256 + threadIdx.x;
  for (int i = threadIdx.x; i < 512; i += 256)
    srow[i >> 6][i & 63] = src[(size_t)m0 * 64 + i];
  __syncthreads();
  float acc[8];
#pragma unroll
  for (int r = 0; r < 8; ++r) acc[r] = bias[n];
  for (int k = 0; k < 64; ++k) {
    const float wv = w[(size_t)k * 512 + n];
#pragma unroll
    for (int r = 0; r < 8; ++r) acc[r] = fmaf(srow[r][k], wv, acc[r]);
  }
  const int i2 = n & ~1;
  const float freq = expf((float)i2 * (-9.210340371976184f / 512.0f));
#pragma unroll
  for (int r = 0; r < 8; ++r) {
    const int pos = (m0 + r) & 1023;
    const float ang = (float)pos * freq;
    acc[r] += (n & 1) ? cosf(ang) : sinf(ang);
    x[(size_t)(m0 + r) * 512 + n] = acc[r];
  }
}

// ---------------------------------------------------------------------------
// RMSNorm fp32-in (one wave per 512-row). GATE: emit per-wave gate partials.
// ---------------------------------------------------------------------------
template <bool BF16OUT, bool GATE>
__global__ __launch_bounds__(256) void rmsnorm_kernel(
    const float* __restrict__ x, const float* __restrict__ scale,
    u16* __restrict__ outb, float* __restrict__ outf,
    const float* __restrict__ gw, float* __restrict__ gp2)
{
  const int wave = threadIdx.x >> 6, lane = threadIdx.x & 63;
  const size_t row = (size_t)blockIdx.x * 4 + wave;
  const f32x4* xr = (const f32x4*)(x + row * 512);
  f32x4 a = xr[lane * 2], c = xr[lane * 2 + 1];
  float ss = a[0]*a[0] + a[1]*a[1] + a[2]*a[2] + a[3]*a[3]
           + c[0]*c[0] + c[1]*c[1] + c[2]*c[2] + c[3]*c[3];
  float dv = 0.0f;
  if (GATE) {
    const f32x4* gr = (const f32x4*)gw;
    f32x4 g1 = gr[lane * 2], g2 = gr[lane * 2 + 1];
    dv = a[0]*g1[0] + a[1]*g1[1] + a[2]*g1[2] + a[3]*g1[3]
       + c[0]*g2[0] + c[1]*g2[1] + c[2]*g2[2] + c[3]*g2[3];
  }
#pragma unroll
  for (int d = 1; d < 64; d <<= 1) {
    ss += __shfl_xor(ss, d);
    if (GATE) dv += __shfl_xor(dv, d);
  }
  if (GATE && lane == 0) gp2[blockIdx.x * 4 + wave] = dv;
  const float r = rsqrtf(ss * (1.0f / 512.0f) + 1e-5f);
  const f32x4* sr = (const f32x4*)scale;
  f32x4 s1 = sr[lane * 2], s2 = sr[lane * 2 + 1];
  if (BF16OUT) {
    u16x8 ov;
    ov[0] = f2bf(a[0] * s1[0] * r); ov[1] = f2bf(a[1] * s1[1] * r);
    ov[2] = f2bf(a[2] * s1[2] * r); ov[3] = f2bf(a[3] * s1[3] * r);
    ov[4] = f2bf(c[0] * s2[0] * r); ov[5] = f2bf(c[1] * s2[1] * r);
    ov[6] = f2bf(c[2] * s2[2] * r); ov[7] = f2bf(c[3] * s2[3] * r);
    *(u16x8*)(outb + row * 512 + lane * 8) = ov;
  } else {
    f32x4 o1, o2;
    o1[0] = a[0]*s1[0]*r; o1[1] = a[1]*s1[1]*r; o1[2] = a[2]*s1[2]*r; o1[3] = a[3]*s1[3]*r;
    o2[0] = c[0]*s2[0]*r; o2[1] = c[1]*s2[1]*r; o2[2] = c[2]*s2[2]*r; o2[3] = c[3]*s2[3]*r;
    f32x4* orow = (f32x4*)(outf + row * 512);
    orow[lane * 2] = o1; orow[lane * 2 + 1] = o2;
  }
}

// RMSNorm bf16-in -> bf16 out (for the y residual stream)
__global__ __launch_bounds__(256) void rmsnorm_b16_kernel(
    const u16* __restrict__ y, const float* __restrict__ scale,
    u16* __restrict__ outb)
{
  const int wave = threadIdx.x >> 6, lane = threadIdx.x & 63;
  const size_t row = (size_t)blockIdx.x * 4 + wave;
  const u16x8 v8 = *(const u16x8*)(y + row * 512 + lane * 8);
  float f[8];
#pragma unroll
  for (int j = 0; j < 8; ++j) f[j] = bf2f(v8[j]);
  float ss = 0.0f;
#pragma unroll
  for (int j = 0; j < 8; ++j) ss += f[j] * f[j];
#pragma unroll
  for (int d = 1; d < 64; d <<= 1) ss += __shfl_xor(ss, d);
  const float r = rsqrtf(ss * (1.0f / 512.0f) + 1e-5f);
  const f32x4* sr = (const f32x4*)scale;
  f32x4 s1 = sr[lane * 2], s2 = sr[lane * 2 + 1];
  u16x8 ov;
  ov[0] = f2bf(f[0] * s1[0] * r); ov[1] = f2bf(f[1] * s1[1] * r);
  ov[2] = f2bf(f[2] * s1[2] * r); ov[3] = f2bf(f[3] * s1[3] * r);
  ov[4] = f2bf(f[4] * s2[0] * r); ov[5] = f2bf(f[5] * s2[1] * r);
  ov[6] = f2bf(f[6] * s2[2] * r); ov[7] = f2bf(f[7] * s2[3] * r);
  *(u16x8*)(outb + row * 512 + lane * 8) = ov;
}

// ---------------------------------------------------------------------------
// GEMM (R7 single-buffer): BM=128, BK=64, BN in {64,128}; 4 waves.
// MODE 0: +bias, cols<512 * 1/8 -> bf16 out                  (QKV)
// MODE 1: +bias + resf(x,f32) -> bf16 out                    (attn out proj)
// MODE 4: gate-reduce + resb(y,bf16) -> f32 out x            (FFN down proj)
// ---------------------------------------------------------------------------
template <int MODE, int BN>
__global__ __launch_bounds__(256) void gemm_bt(
    const u16* __restrict__ A, const u16* __restrict__ Bt,
    const float* __restrict__ bias, const float* __restrict__ resf,
    const u16* __restrict__ resb, float* __restrict__ outf,
    u16* __restrict__ outb, const float* __restrict__ gatep,
    const float* __restrict__ gbias, int layer, int M, int N, int K)
{
  constexpr int NI = BN / 32;
  __shared__ __align__(16) u16 lA[128 * 64];
  __shared__ __align__(16) u16 lB[BN * 64];
  const int tid = threadIdx.x;
  const int wave = tid >> 6, lane = tid & 63;
  const int lr = lane & 15, lg = lane >> 4;
  int bx = blockIdx.x, by = blockIdx.y;
  xcd_map(bx, by);
  const int m0 = by << 7, n0 = bx * BN;
  const int wr = wave >> 1, wc = wave & 1;
  if (MODE == 4) {
    __shared__ float red[64];
    __shared__ float gfl;
    const float* g4 = gatep + (size_t)(m0 >> 10) * 256;
    float v = (tid < 256) ? g4[tid] : 0.0f;
#pragma unroll
    for (int d = 1; d < 64; d <<= 1) v += __shfl_xor(v, d);
    if (lane == 0) red[wave] = v;
    __syncthreads();
    if (tid == 0) {
      const float s = red[0] + red[1] + red[2] + red[3];
      gfl = (s / 1024.0f + gbias[layer] > 0.0f) ? 1.0f : 0.0f;
    }
    __syncthreads();
    if (gfl == 0.0f) return;
  }
  f32x4 acc[4][NI] = {};
  for (int kt = 0; kt < K; kt += 64) {
    __syncthreads();
#pragma unroll
    for (int i = 0; i < 4; ++i) {
      const int c = i * 256 + tid;
      const int row = c >> 3, kc = ((c & 7) ^ (row & 7)) << 3;
      gload16(A + (size_t)(m0 + row) * K + kt + kc,
              lA + (size_t)(i * 256 + wave * 64) * 8);
    }
#pragma unroll
    for (int i = 0; i < BN / 32; ++i) {
      const int c = i * 256 + tid;
      const int row = c >> 3, kc = ((c & 7) ^ (row & 7)) << 3;
      gload16(Bt + (size_t)(n0 + row) * K + kt + kc,
              lB + (size_t)(i * 256 + wave * 64) * 8);
    }
    __syncthreads();
    bf16x8 af[2][4], bfr[2][NI];
#pragma unroll
    for (int kk = 0; kk < 2; ++kk) {
#pragma unroll
      for (int mi = 0; mi < 4; ++mi) {
        const int row = wr * 64 + mi * 16 + lr;
        af[kk][mi] = *(const bf16x8*)&lA[row * 64 + (((kk * 4 + lg) ^ (row & 7)) << 3)];
      }
#pragma unroll
      for (int ni = 0; ni < NI; ++ni) {
        const int row = wc * (BN / 2) + ni * 16 + lr;
        bfr[kk][ni] = *(const bf16x8*)&lB[row * 64 + (((kk * 4 + lg) ^ (row & 7)) << 3)];
      }
    }
#pragma unroll
    for (int kk = 0; kk < 2; ++kk)
#pragma unroll
      for (int mi = 0; mi < 4; ++mi)
#pragma unroll
        for (int ni = 0; ni < NI; ++ni)
          acc[mi][ni] = __builtin_amdgcn_mfma_f32_16x16x32_bf16(
              af[kk][mi], bfr[kk][ni], acc[mi][ni], 0, 0, 0);
  }
#pragma unroll
  for (int mi = 0; mi < 4; ++mi) {
#pragma unroll
    for (int ni = 0; ni < NI; ++ni) {
      const int col = n0 + wc * (BN / 2) + ni * 16 + lr;
      const float bs = (MODE == 0 || MODE == 1) ? bias[col] : 0.0f;
#pragma unroll
      for (int j = 0; j < 4; ++j) {
        const int row = m0 + wr * 64 + mi * 16 + lg * 4 + j;
        const size_t idx = (size_t)row * N + col;
        float v = acc[mi][ni][j] + bs;
        if (MODE == 0) {
          if (col < 512) v *= 0.125f;
          outb[idx] = f2bf(v);
        } else if (MODE == 1) {
          outb[idx] = f2bf(v + resf[idx]);     // y (bf16) = x + ctx@Wo
        } else {                               // MODE 4
          outf[idx] = v + bf2f(resb[idx]);     // x (f32) = ffn + y
        }
      }
    }
  }
}

// ---------------------------------------------------------------------------
// Fused SwiGLU FFN front (R10 form): T = silu(A@WgT^T) * (A@WuT^T), bf16.
// M=8192, N=2048, K=512. BM=128, BN=64, BK=64; 2-phase; 2D XCD tiling.
// ---------------------------------------------------------------------------
__global__ __launch_bounds__(256) void gemm_glu(
    const u16* __restrict__ A, const u16* __restrict__ Bg,
    const u16* __restrict__ Bu, u16* __restrict__ outT)
{
  constexpr int K = 512, N = 2048;
  __shared__ __align__(16) u16 lA[128 * 64];
  __shared__ __align__(16) u16 lG[64 * 64];
  __shared__ __align__(16) u16 lU[64 * 64];
  const int tid = threadIdx.x;
  const int wave = tid >> 6, lane = tid & 63;
  const int lr = lane & 15, lg = lane >> 4;
  const int orig = blockIdx.y * gridDim.x + blockIdx.x;
  const int xcd = orig & 7, rnk = orig >> 3;
  const int bx = (xcd & 1) * 16 + (rnk >> 4);
  const int by = (xcd >> 1) * 16 + (rnk & 15);
  const int m0 = by << 7, n0 = bx << 6;
  const int wr = wave >> 1, wc = wave & 1;
  f32x4 ag[4][2] = {}, au[4][2] = {};
  for (int kt = 0; kt < K; kt += 64) {
    __syncthreads();
#pragma unroll
    for (int i = 0; i < 4; ++i) {
      const int c = i * 256 + tid;
      const int row = c >> 3, kc = ((c & 7) ^ (row & 7)) << 3;
      gload16(A + (size_t)(m0 + row) * K + kt + kc,
              lA + (size_t)(i * 256 + wave * 64) * 8);
    }
#pragma unroll
    for (int i = 0; i < 2; ++i) {
      const int c = i * 256 + tid;
      const int row = c >> 3, kc = ((c & 7) ^ (row & 7)) << 3;
      const size_t dst = (size_t)(i * 256 + wave * 64) * 8;
      gload16(Bg + (size_t)(n0 + row) * K + kt + kc, lG + dst);
      gload16(Bu + (size_t)(n0 + row) * K + kt + kc, lU + dst);
    }
    __syncthreads();
    bf16x8 af[2][4], gf[2][2], uf[2][2];
#pragma unroll
    for (int kk = 0; kk < 2; ++kk) {
#pragma unroll
      for (int mi = 0; mi < 4; ++mi) {
        const int row = wr * 64 + mi * 16 + lr;
        af[kk][mi] = *(const bf16x8*)&lA[row * 64 + (((kk * 4 + lg) ^ (row & 7)) << 3)];
      }
#pragma unroll
      for (int ni = 0; ni < 2; ++ni) {
        const int row = wc * 32 + ni * 16 + lr;
        const int off = row * 64 + (((kk * 4 + lg) ^ (row & 7)) << 3);
        gf[kk][ni] = *(const bf16x8*)&lG[off];
        uf[kk][ni] = *(const bf16x8*)&lU[off];
      }
    }
#pragma unroll
    for (int kk = 0; kk < 2; ++kk)
#pragma unroll
      for (int mi = 0; mi < 4; ++mi)
#pragma unroll
        for (int ni = 0; ni < 2; ++ni) {
          ag[mi][ni] = __builtin_amdgcn_mfma_f32_16x16x32_bf16(
              af[kk][mi], gf[kk][ni], ag[mi][ni], 0, 0, 0);
          au[mi][ni] = __builtin_amdgcn_mfma_f32_16x16x32_bf16(
              af[kk][mi], uf[kk][ni], au[mi][ni], 0, 0, 0);
        }
  }
#pragma unroll
  for (int mi = 0; mi < 4; ++mi) {
#pragma unroll
    for (int ni = 0; ni < 2; ++ni) {
      const int col = n0 + wc * 32 + ni * 16 + lr;
#pragma unroll
      for (int j = 0; j < 4; ++j) {
        const int row = m0 + wr * 64 + mi * 16 + lg * 4 + j;
        const float g = ag[mi][ni][j];
        const float sg = g / (1.0f + __expf(-g));
        outT[(size_t)row * N + col] = f2bf(sg * au[mi][ni][j]);
      }
    }
  }
}

// ---------------------------------------------------------------------------
// Flash attention, swapped 32x32x16 structure (verified R4; pipelined R6;
// Vsh both-sides XOR R14). R15: XCD map co-locates a (b,h)'s 8 q-blocks on
// one XCD -> K/V (2MB/XCD) stays L2-resident.
// ---------------------------------------------------------------------------
__global__ __launch_bounds__(256) void attn_kernel(
    const u16* __restrict__ qkv, u16* __restrict__ ctx)
{
  constexpr int LD = 1536;
  // grid (8, 64) linearized; XCD k owns bh in [8k, 8k+8), all 8 qblks each.
  const int orig = blockIdx.y * 8 + blockIdx.x;
  const int xcd = orig & 7, rnk = orig >> 3;
  const int bh = xcd * 8 + (rnk >> 3);
  const int qblk = rnk & 7;
  const int b = bh >> 3, h = bh & 7;
  const int tid = threadIdx.x, wave = tid >> 6, lane = tid & 63;
  const int l31 = lane & 31, half = lane >> 5;
  const size_t rowb = (size_t)b * 1024;
  const int q0 = qblk * 128 + wave * 32;

  __shared__ __align__(16) u16 Ksh[2][64 * 64];
  __shared__ __align__(16) u16 Vsh[2][64 * 72];   // [d][key], 144B rows
  __shared__ __align__(16) u16 PL[4][32 * 64];

  const u16* qrow = qkv + (rowb + q0 + l31) * LD + h * 64;
  bf16x8 qf[4];
#pragma unroll
  for (int c = 0; c < 4; ++c)
    qf[c] = *(const bf16x8*)(qrow + c * 16 + half * 8);

  const int krow0 = tid >> 3;
  const int kch0 = (tid & 7) ^ (krow0 & 7);
  const int vm = tid >> 3, vd0 = (tid & 7) * 8;
  const int vcol = (((vm >> 2) ^ (tid & 7)) << 4) + ((vm & 3) << 2);
  char* vbase0 = (char*)Vsh[0] + vcol;
  const u16* kg = qkv + rowb * LD + 512 + h * 64;
  const u16* vg = qkv + (rowb + 2 * vm) * LD + 1024 + h * 64 + vd0;

  f32x16 o0 = {}, o1 = {};
  float l_acc = 0.0f;

  gload16(kg + (size_t)(0 + krow0) * LD + kch0 * 8, Ksh[0] + wave * 512);
  gload16(kg + (size_t)(32 + krow0) * LD + kch0 * 8, Ksh[0] + 2048 + wave * 512);
  {
    u16x8 va = *(const u16x8*)vg;
    u16x8 vb = *(const u16x8*)(vg + LD);
#pragma unroll
    for (int j = 0; j < 8; ++j) {
      *(unsigned*)(vbase0 + (vd0 + j) * 144) =
          (unsigned)va[j] | ((unsigned)vb[j] << 16);
    }
  }
  __syncthreads();

  for (int t = 0; t < 16; ++t) {
    const int cur = t & 1, nxt = cur ^ 1;
    const int k0n = (t + 1) * 64;
    u16x8 va2, vb2;
    if (t < 15) {
      gload16(kg + (size_t)(k0n + krow0) * LD + kch0 * 8,
              Ksh[nxt] + wave * 512);
      gload16(kg + (size_t)(k0n + 32 + krow0) * LD + kch0 * 8,
              Ksh[nxt] + 2048 + wave * 512);
      va2 = *(const u16x8*)(vg + (size_t)k0n * LD);
      vb2 = *(const u16x8*)(vg + (size_t)k0n * LD + LD);
    }

    const char* kshb = (const char*)Ksh[cur];
    const char* vshb = (const char*)Vsh[cur];

    f32x16 s0 = {}, s1 = {};
#pragma unroll
    for (int c = 0; c < 4; ++c) {
      {
        const int row = l31;
        bf16x8 kf = *(const bf16x8*)(kshb + row * 128 +
                        ((((c << 1) | half) ^ (row & 7)) << 4));
        s0 = __builtin_amdgcn_mfma_f32_32x32x16_bf16(kf, qf[c], s0, 0, 0, 0);
      }
      {
        const int row = 32 + l31;
        bf16x8 kf = *(const bf16x8*)(kshb + row * 128 +
                        ((((c << 1) | half) ^ (row & 7)) << 4));
        s1 = __builtin_amdgcn_mfma_f32_32x32x16_bf16(kf, qf[c], s1, 0, 0, 0);
      }
    }

    char* plw = (char*)PL[wave];
#pragma unroll
    for (int blk = 0; blk < 2; ++blk) {
      const f32x16 sv = blk ? s1 : s0;
#pragma unroll
      for (int rg = 0; rg < 4; ++rg) {
        const float e0 = __expf(fminf(sv[rg * 4 + 0], 60.0f));
        const float e1 = __expf(fminf(sv[rg * 4 + 1], 60.0f));
        const float e2 = __expf(fminf(sv[rg * 4 + 2], 60.0f));
        const float e3 = __expf(fminf(sv[rg * 4 + 3], 60.0f));
        l_acc += (e0 + e1) + (e2 + e3);
        const unsigned lo = pk2(e0, e1);
        const unsigned hi = pk2(e2, e3);
        const int chunk = (rg + 4 * blk) ^ (l31 & 7);
        *(unsigned long long*)(plw + l31 * 128 + (chunk << 4) + half * 8) =
            (unsigned long long)lo | ((unsigned long long)hi << 32);
      }
    }

#pragma unroll
    for (int c = 0; c < 4; ++c) {
      bf16x8 pf = *(const bf16x8*)(plw + l31 * 128 +
                      ((((c << 1) | half) ^ (l31 & 7)) << 4));
      {
        const int row = l31;
        bf16x8 vf = *(const bf16x8*)(vshb + row * 144 +
                        ((((c << 1) | half) ^ (row >> 3)) << 4));
        o0 = __builtin_amdgcn_mfma_f32_32x32x16_bf16(pf, vf, o0, 0, 0, 0);
      }
      {
        const int row = 32 + l31;
        bf16x8 vf = *(const bf16x8*)(vshb + row * 144 +
                        ((((c << 1) | half) ^ (row >> 3)) << 4));
        o1 = __builtin_amdgcn_mfma_f32_32x32x16_bf16(pf, vf, o1, 0, 0, 0);
      }
    }

    if (t < 15) {
      char* vbn = (char*)Vsh[nxt] + vcol;
#pragma unroll
      for (int j = 0; j < 8; ++j) {
        *(unsigned*)(vbn + (vd0 + j) * 144) =
            (unsigned)va2[j] | ((unsigned)vb2[j] << 16);
      }
    }
    __syncthreads();
  }

  // epilogue: lane q (q<32) holds l_acc for q; combine halves, shfl rl.
  const float l_tot = l_acc + __shfl_xor(l_acc, 32);
  const float rl_all = 1.0f / l_tot;
#pragma unroll
  for (int r = 0; r < 16; ++r) {
    const int q_r = (r & 3) + 8 * (r >> 2) + 4 * half;
    const float rl = __shfl(rl_all, q_r);
    const size_t orow = (rowb + q0 + q_r) * 512 + h * 64 + l31;
    ctx[orow] = f2bf(o0[r] * rl);
    ctx[orow + 32] = f2bf(o1[r] * rl);
  }
}

// ---------------------------------------------------------------------------
extern "C" void kernel_launch(void* const* d_in, const int* in_sizes, int n_in,
                              void* d_out, int out_size, void* d_ws, size_t ws_size,
                              hipStream_t stream)
{
  (void)in_sizes; (void)n_in; (void)out_size; (void)ws_size;
  const float* src  = (const float*)d_in[0];
  const float* in_w = (const float*)d_in[1];
  const float* in_b = (const float*)d_in[2];
  const float* Wq   = (const float*)d_in[3];
  const float* Wk   = (const float*)d_in[4];
  const float* Wv   = (const float*)d_in[5];
  const float* Wo   = (const float*)d_in[6];
  const float* bq   = (const float*)d_in[7];
  const float* bk   = (const float*)d_in[8];
  const float* bv   = (const float*)d_in[9];
  const float* bo   = (const float*)d_in[10];
  const float* n1   = (const float*)d_in[11];
  const float* n2   = (const float*)d_in[12];
  const float* Wg   = (const float*)d_in[13];
  const float* Wu   = (const float*)d_in[14];
  const float* Wd   = (const float*)d_in[15];
  const float* gw   = (const float*)d_in[16];
  const float* gb   = (const float*)d_in[17];
  const float* fs   = (const float*)d_in[18];

  char* ws = (char*)d_ws;
  size_t off = 0;
  auto alloc = [&](size_t bytes) -> void* {
    void* p = ws + off;
    off += (bytes + 255) & ~(size_t)255;
    return p;
  };
  u16*   WqkvT = (u16*)alloc(6ULL * 1536 * 512 * 2);
  u16*   WoT   = (u16*)alloc(6ULL * 512 * 512 * 2);
  u16*   WgT   = (u16*)alloc(6ULL * 2048 * 512 * 2);
  u16*   WuT   = (u16*)alloc(6ULL * 2048 * 512 * 2);
  u16*   WdT   = (u16*)alloc(6ULL * 512 * 2048 * 2);
  float* bqkv  = (float*)alloc(6ULL * 1536 * 4);
  float* x     = (float*)alloc(8192ULL * 512 * 4);
  u16*   y     = (u16*)alloc(8192ULL * 512 * 2);   // bf16 residual y
  u16*   hbuf  = (u16*)alloc(8192ULL * 512 * 2);
  u16*   sA    = (u16*)alloc(8192ULL * 2048 * 2);
  u16*   sB    = (u16*)alloc(8192ULL * 2048 * 2);
  float* gp2   = (float*)alloc(8192 * 4);

  const dim3 tb(256);
  transpose_all_kernel<<<dim3(4096, 6), tb, 0, stream>>>(
      Wq, Wk, Wv, Wo, Wg, Wu, Wd, WqkvT, WoT, WgT, WuT, WdT);
  biaspack_kernel<<<6, tb, 0, stream>>>(bq, bk, bv, bqkv);
  adapter_kernel<<<dim3(2, 1024), tb, 0, stream>>>(src, in_w, in_b, x);

  for (int l = 0; l < 6; ++l) {
    rmsnorm_kernel<true, true><<<2048, tb, 0, stream>>>(
        x, n1 + l * 512, hbuf, nullptr, gw + l * 512, gp2);
    gemm_bt<0, 128><<<dim3(12, 64), tb, 0, stream>>>(
        hbuf, WqkvT + (size_t)l * 1536 * 512, bqkv + l * 1536,
        nullptr, nullptr, nullptr, sA, nullptr, nullptr, 0, 8192, 1536, 512);
    attn_kernel<<<dim3(8, 64), tb, 0, stream>>>(sA, sB);
    gemm_bt<1, 64><<<dim3(8, 64), tb, 0, stream>>>(
        sB, WoT + (size_t)l * 512 * 512, bo + l * 512,
        x, nullptr, nullptr, y, nullptr, nullptr, 0, 8192, 512, 512);
    rmsnorm_b16_kernel<<<2048, tb, 0, stream>>>(y, n2 + l * 512, hbuf);
    gemm_glu<<<dim3(32, 64), tb, 0, stream>>>(
        hbuf, WgT + (size_t)l * 2048 * 512, WuT + (size_t)l * 2048 * 512, sB);
    gemm_bt<4, 64><<<dim3(8, 64), tb, 0, stream>>>(
        sB, WdT + (size_t)l * 512 * 2048, nullptr,
        nullptr, y, x, nullptr, gp2, gb, l, 8192, 512, 2048);
  }
  rmsnorm_kernel<false, false><<<2048, tb, 0, stream>>>(
      x, fs, nullptr, (float*)d_out, nullptr, nullptr);
}

// Round 17
// 953.612 us; speedup vs baseline: 1.0195x; 1.0195x over previous
//
#include <hip/hip_runtime.h>

// ---------------------------------------------------------------------------
// TransformerEncoder on MI355X (gfx950).
// B=8 S=1024 IN=64 D=512 F=2048 H=8 HD=64 L=6. All inputs fp32, output fp32.
// R17 (= R16 with compile fix): attn softmax VALU cut: Q pre-scaled by
//      log2e/8 in QKV epilogue -> p = exp2(s) via __builtin_amdgcn_exp2f
//      (raw v_exp_f32, no mul); clamp dropped (scores ~|2| by construction).
// ---------------------------------------------------------------------------

typedef unsigned short u16;
typedef __attribute__((ext_vector_type(8))) __bf16 bf16x8;
typedef __attribute__((ext_vector_type(2))) __bf16 bf16x2;
typedef __attribute__((ext_vector_type(4))) float f32x4;
typedef __attribute__((ext_vector_type(16))) float f32x16;
typedef __attribute__((ext_vector_type(8))) unsigned short u16x8;

#define DEV __device__ __forceinline__

DEV u16 f2bf(float f) {               // native RNE cast (HW v_cvt)
  __bf16 h = (__bf16)f;
  return __builtin_bit_cast(u16, h);
}
DEV float bf2f(u16 h) { return __builtin_bit_cast(float, ((unsigned)h) << 16); }
DEV unsigned pk2(float a, float b) {  // pack 2 floats -> 2 bf16 (cvt_pk)
  bf16x2 v; v[0] = (__bf16)a; v[1] = (__bf16)b;
  return __builtin_bit_cast(unsigned, v);
}

DEV void gload16(const void* g, void* l) {
  __builtin_amdgcn_global_load_lds(
      (__attribute__((address_space(1))) void*)g,
      (__attribute__((address_space(3))) void*)l, 16, 0, 0);
}

// XCD chunked swizzle: XCD owns contiguous by-strip, all bx.
DEV void xcd_map(int& bx, int& by) {
  const int nx = gridDim.x, ny = gridDim.y;
  const int orig = by * nx + bx;
  const int cpx = (nx * ny) >> 3;
  const int swz = (orig & 7) * cpx + (orig >> 3);
  by = swz / nx; bx = swz - by * nx;
}

// ---------------------------------------------------------------------------
// Batched weight transpose fp32 [K][N] -> bf16 [N][K], all weights, all layers.
// ---------------------------------------------------------------------------
__global__ __launch_bounds__(256) void transpose_all_kernel(
    const float* __restrict__ Wq, const float* __restrict__ Wk,
    const float* __restrict__ Wv, const float* __restrict__ Wo,
    const float* __restrict__ Wg, const float* __restrict__ Wu,
    const float* __restrict__ Wd,
    u16* __restrict__ WqkvT, u16* __restrict__ WoT, u16* __restrict__ WgT,
    u16* __restrict__ WuT, u16* __restrict__ WdT)
{
  const int l = blockIdx.y;
  const int idx = blockIdx.x;
  const float* src; u16* dst; int N, bx, by;
  if (idx < 1024) {
    const int w = idx >> 8, t = idx & 255;
    bx = t & 15; by = t >> 4; N = 512;
    const size_t lo = (size_t)l * 262144;
    if (w == 0)      { src = Wq + lo; dst = WqkvT + (size_t)l * 786432; }
    else if (w == 1) { src = Wk + lo; dst = WqkvT + (size_t)l * 786432 + 262144; }
    else if (w == 2) { src = Wv + lo; dst = WqkvT + (size_t)l * 786432 + 524288; }
    else             { src = Wo + lo; dst = WoT + lo; }
  } else if (idx < 2048) {
    const int t = idx - 1024; bx = t & 63; by = t >> 6; N = 2048;
    src = Wg + (size_t)l * 1048576; dst = WgT + (size_t)l * 1048576;
  } else if (idx < 3072) {
    const int t = idx - 2048; bx = t & 63; by = t >> 6; N = 2048;
    src = Wu + (size_t)l * 1048576; dst = WuT + (size_t)l * 1048576;
  } else {
    const int t = idx - 3072; bx = t & 15; by = t >> 4; N = 512;
    src = Wd + (size_t)l * 1048576; dst = WdT + (size_t)l * 1048576;
  }
  const int K = (idx >= 3072) ? 2048 : 512;
  __shared__ float tl[32][33];
  const int n0 = bx * 32, k0 = by * 32;
  const int tx = threadIdx.x & 31, ty = threadIdx.x >> 5;
#pragma unroll
  for (int i = 0; i < 4; ++i)
    tl[ty + i * 8][tx] = src[(size_t)(k0 + ty + i * 8) * N + n0 + tx];
  __syncthreads();
#pragma unroll
  for (int i = 0; i < 4; ++i)
    dst[(size_t)(n0 + ty + i * 8) * K + k0 + tx] = f2bf(tl[tx][ty + i * 8]);
}

// pack bq|bk|bv into [L][1536]
__global__ void biaspack_kernel(const float* __restrict__ bq,
                                const float* __restrict__ bk,
                                const float* __restrict__ bv,
                                float* __restrict__ out)
{
  const int l = blockIdx.x;
  for (int c = threadIdx.x; c < 1536; c += 256) {
    float v = (c < 512) ? bq[l * 512 + c]
            : (c < 1024) ? bk[l * 512 + c - 512]
                         : bv[l * 512 + c - 1024];
    out[l * 1536 + c] = v;
  }
}

// ---------------------------------------------------------------------------
// Input adapter: x = src @ in_w + in_b + sinusoidal_pe   (fp32, [8192][512])
// ---------------------------------------------------------------------------
__global__ __launch_bounds__(256) void adapter_kernel(
    const float* __restrict__ src, const float* __restrict__ w,
    const float* __restrict__ bias, float* __restrict__ x)
{
  __shared__ float srow[8][64];
  const int m0 = blockIdx.y * 8;
  const int n = blockIdx.x * 256 + threadIdx.x;
  for (int i = threadIdx.x; i < 512; i += 256)
    srow[i >> 6][i & 63] = src[(size_t)m0 * 64 + i];
  __syncthreads();
  float acc[8];
#pragma unroll
  for (int r = 0; r < 8; ++r) acc[r] = bias[n];
  for (int k = 0; k < 64; ++k) {
    const float wv = w[(size_t)k * 512 + n];
#pragma unroll
    for (int r = 0; r < 8; ++r) acc[r] = fmaf(srow[r][k], wv, acc[r]);
  }
  const int i2 = n & ~1;
  const float freq = expf((float)i2 * (-9.210340371976184f / 512.0f));
#pragma unroll
  for (int r = 0; r < 8; ++r) {
    const int pos = (m0 + r) & 1023;
    const float ang = (float)pos * freq;
    acc[r] += (n & 1) ? cosf(ang) : sinf(ang);
    x[(size_t)(m0 + r) * 512 + n] = acc[r];
  }
}

// ---------------------------------------------------------------------------
// RMSNorm fp32-in (one wave per 512-row). GATE: emit per-wave gate partials.
// ---------------------------------------------------------------------------
template <bool BF16OUT, bool GATE>
__global__ __launch_bounds__(256) void rmsnorm_kernel(
    const float* __restrict__ x, const float* __restrict__ scale,
    u16* __restrict__ outb, float* __restrict__ outf,
    const float* __restrict__ gw, float* __restrict__ gp2)
{
  const int wave = threadIdx.x >> 6, lane = threadIdx.x & 63;
  const size_t row = (size_t)blockIdx.x * 4 + wave;
  const f32x4* xr = (const f32x4*)(x + row * 512);
  f32x4 a = xr[lane * 2], c = xr[lane * 2 + 1];
  float ss = a[0]*a[0] + a[1]*a[1] + a[2]*a[2] + a[3]*a[3]
           + c[0]*c[0] + c[1]*c[1] + c[2]*c[2] + c[3]*c[3];
  float dv = 0.0f;
  if (GATE) {
    const f32x4* gr = (const f32x4*)gw;
    f32x4 g1 = gr[lane * 2], g2 = gr[lane * 2 + 1];
    dv = a[0]*g1[0] + a[1]*g1[1] + a[2]*g1[2] + a[3]*g1[3]
       + c[0]*g2[0] + c[1]*g2[1] + c[2]*g2[2] + c[3]*g2[3];
  }
#pragma unroll
  for (int d = 1; d < 64; d <<= 1) {
    ss += __shfl_xor(ss, d);
    if (GATE) dv += __shfl_xor(dv, d);
  }
  if (GATE && lane == 0) gp2[blockIdx.x * 4 + wave] = dv;
  const float r = rsqrtf(ss * (1.0f / 512.0f) + 1e-5f);
  const f32x4* sr = (const f32x4*)scale;
  f32x4 s1 = sr[lane * 2], s2 = sr[lane * 2 + 1];
  if (BF16OUT) {
    u16x8 ov;
    ov[0] = f2bf(a[0] * s1[0] * r); ov[1] = f2bf(a[1] * s1[1] * r);
    ov[2] = f2bf(a[2] * s1[2] * r); ov[3] = f2bf(a[3] * s1[3] * r);
    ov[4] = f2bf(c[0] * s2[0] * r); ov[5] = f2bf(c[1] * s2[1] * r);
    ov[6] = f2bf(c[2] * s2[2] * r); ov[7] = f2bf(c[3] * s2[3] * r);
    *(u16x8*)(outb + row * 512 + lane * 8) = ov;
  } else {
    f32x4 o1, o2;
    o1[0] = a[0]*s1[0]*r; o1[1] = a[1]*s1[1]*r; o1[2] = a[2]*s1[2]*r; o1[3] = a[3]*s1[3]*r;
    o2[0] = c[0]*s2[0]*r; o2[1] = c[1]*s2[1]*r; o2[2] = c[2]*s2[2]*r; o2[3] = c[3]*s2[3]*r;
    f32x4* orow = (f32x4*)(outf + row * 512);
    orow[lane * 2] = o1; orow[lane * 2 + 1] = o2;
  }
}

// RMSNorm bf16-in -> bf16 out (for the y residual stream)
__global__ __launch_bounds__(256) void rmsnorm_b16_kernel(
    const u16* __restrict__ y, const float* __restrict__ scale,
    u16* __restrict__ outb)
{
  const int wave = threadIdx.x >> 6, lane = threadIdx.x & 63;
  const size_t row = (size_t)blockIdx.x * 4 + wave;
  const u16x8 v8 = *(const u16x8*)(y + row * 512 + lane * 8);
  float f[8];
#pragma unroll
  for (int j = 0; j < 8; ++j) f[j] = bf2f(v8[j]);
  float ss = 0.0f;
#pragma unroll
  for (int j = 0; j < 8; ++j) ss += f[j] * f[j];
#pragma unroll
  for (int d = 1; d < 64; d <<= 1) ss += __shfl_xor(ss, d);
  const float r = rsqrtf(ss * (1.0f / 512.0f) + 1e-5f);
  const f32x4* sr = (const f32x4*)scale;
  f32x4 s1 = sr[lane * 2], s2 = sr[lane * 2 + 1];
  u16x8 ov;
  ov[0] = f2bf(f[0] * s1[0] * r); ov[1] = f2bf(f[1] * s1[1] * r);
  ov[2] = f2bf(f[2] * s1[2] * r); ov[3] = f2bf(f[3] * s1[3] * r);
  ov[4] = f2bf(f[4] * s2[0] * r); ov[5] = f2bf(f[5] * s2[1] * r);
  ov[6] = f2bf(f[6] * s2[2] * r); ov[7] = f2bf(f[7] * s2[3] * r);
  *(u16x8*)(outb + row * 512 + lane * 8) = ov;
}

// ---------------------------------------------------------------------------
// GEMM (R7 single-buffer): BM=128, BK=64, BN in {64,128}; 4 waves.
// MODE 0: +bias, cols<512 * log2e/8 -> bf16 out              (QKV)
// MODE 1: +bias + resf(x,f32) -> bf16 out                    (attn out proj)
// MODE 4: gate-reduce + resb(y,bf16) -> f32 out x            (FFN down proj)
// ---------------------------------------------------------------------------
template <int MODE, int BN>
__global__ __launch_bounds__(256) void gemm_bt(
    const u16* __restrict__ A, const u16* __restrict__ Bt,
    const float* __restrict__ bias, const float* __restrict__ resf,
    const u16* __restrict__ resb, float* __restrict__ outf,
    u16* __restrict__ outb, const float* __restrict__ gatep,
    const float* __restrict__ gbias, int layer, int M, int N, int K)
{
  constexpr int NI = BN / 32;
  __shared__ __align__(16) u16 lA[128 * 64];
  __shared__ __align__(16) u16 lB[BN * 64];
  const int tid = threadIdx.x;
  const int wave = tid >> 6, lane = tid & 63;
  const int lr = lane & 15, lg = lane >> 4;
  int bx = blockIdx.x, by = blockIdx.y;
  xcd_map(bx, by);
  const int m0 = by << 7, n0 = bx * BN;
  const int wr = wave >> 1, wc = wave & 1;
  if (MODE == 4) {
    __shared__ float red[64];
    __shared__ float gfl;
    const float* g4 = gatep + (size_t)(m0 >> 10) * 256;
    float v = (tid < 256) ? g4[tid] : 0.0f;
#pragma unroll
    for (int d = 1; d < 64; d <<= 1) v += __shfl_xor(v, d);
    if (lane == 0) red[wave] = v;
    __syncthreads();
    if (tid == 0) {
      const float s = red[0] + red[1] + red[2] + red[3];
      gfl = (s / 1024.0f + gbias[layer] > 0.0f) ? 1.0f : 0.0f;
    }
    __syncthreads();
    if (gfl == 0.0f) return;
  }
  f32x4 acc[4][NI] = {};
  for (int kt = 0; kt < K; kt += 64) {
    __syncthreads();
#pragma unroll
    for (int i = 0; i < 4; ++i) {
      const int c = i * 256 + tid;
      const int row = c >> 3, kc = ((c & 7) ^ (row & 7)) << 3;
      gload16(A + (size_t)(m0 + row) * K + kt + kc,
              lA + (size_t)(i * 256 + wave * 64) * 8);
    }
#pragma unroll
    for (int i = 0; i < BN / 32; ++i) {
      const int c = i * 256 + tid;
      const int row = c >> 3, kc = ((c & 7) ^ (row & 7)) << 3;
      gload16(Bt + (size_t)(n0 + row) * K + kt + kc,
              lB + (size_t)(i * 256 + wave * 64) * 8);
    }
    __syncthreads();
    bf16x8 af[2][4], bfr[2][NI];
#pragma unroll
    for (int kk = 0; kk < 2; ++kk) {
#pragma unroll
      for (int mi = 0; mi < 4; ++mi) {
        const int row = wr * 64 + mi * 16 + lr;
        af[kk][mi] = *(const bf16x8*)&lA[row * 64 + (((kk * 4 + lg) ^ (row & 7)) << 3)];
      }
#pragma unroll
      for (int ni = 0; ni < NI; ++ni) {
        const int row = wc * (BN / 2) + ni * 16 + lr;
        bfr[kk][ni] = *(const bf16x8*)&lB[row * 64 + (((kk * 4 + lg) ^ (row & 7)) << 3)];
      }
    }
#pragma unroll
    for (int kk = 0; kk < 2; ++kk)
#pragma unroll
      for (int mi = 0; mi < 4; ++mi)
#pragma unroll
        for (int ni = 0; ni < NI; ++ni)
          acc[mi][ni] = __builtin_amdgcn_mfma_f32_16x16x32_bf16(
              af[kk][mi], bfr[kk][ni], acc[mi][ni], 0, 0, 0);
  }
#pragma unroll
  for (int mi = 0; mi < 4; ++mi) {
#pragma unroll
    for (int ni = 0; ni < NI; ++ni) {
      const int col = n0 + wc * (BN / 2) + ni * 16 + lr;
      const float bs = (MODE == 0 || MODE == 1) ? bias[col] : 0.0f;
#pragma unroll
      for (int j = 0; j < 4; ++j) {
        const int row = m0 + wr * 64 + mi * 16 + lg * 4 + j;
        const size_t idx = (size_t)row * N + col;
        float v = acc[mi][ni][j] + bs;
        if (MODE == 0) {
          // Q pre-scale: 1/sqrt(HD) * log2(e)  (softmax uses exp2 directly)
          if (col < 512) v *= 0.18033688011112042f;
          outb[idx] = f2bf(v);
        } else if (MODE == 1) {
          outb[idx] = f2bf(v + resf[idx]);     // y (bf16) = x + ctx@Wo
        } else {                               // MODE 4
          outf[idx] = v + bf2f(resb[idx]);     // x (f32) = ffn + y
        }
      }
    }
  }
}

// ---------------------------------------------------------------------------
// Fused SwiGLU FFN front (R10 form): T = silu(A@WgT^T) * (A@WuT^T), bf16.
// M=8192, N=2048, K=512. BM=128, BN=64, BK=64; 2-phase; 2D XCD tiling.
// ---------------------------------------------------------------------------
__global__ __launch_bounds__(256) void gemm_glu(
    const u16* __restrict__ A, const u16* __restrict__ Bg,
    const u16* __restrict__ Bu, u16* __restrict__ outT)
{
  constexpr int K = 512, N = 2048;
  __shared__ __align__(16) u16 lA[128 * 64];
  __shared__ __align__(16) u16 lG[64 * 64];
  __shared__ __align__(16) u16 lU[64 * 64];
  const int tid = threadIdx.x;
  const int wave = tid >> 6, lane = tid & 63;
  const int lr = lane & 15, lg = lane >> 4;
  const int orig = blockIdx.y * gridDim.x + blockIdx.x;
  const int xcd = orig & 7, rnk = orig >> 3;
  const int bx = (xcd & 1) * 16 + (rnk >> 4);
  const int by = (xcd >> 1) * 16 + (rnk & 15);
  const int m0 = by << 7, n0 = bx << 6;
  const int wr = wave >> 1, wc = wave & 1;
  f32x4 ag[4][2] = {}, au[4][2] = {};
  for (int kt = 0; kt < K; kt += 64) {
    __syncthreads();
#pragma unroll
    for (int i = 0; i < 4; ++i) {
      const int c = i * 256 + tid;
      const int row = c >> 3, kc = ((c & 7) ^ (row & 7)) << 3;
      gload16(A + (size_t)(m0 + row) * K + kt + kc,
              lA + (size_t)(i * 256 + wave * 64) * 8);
    }
#pragma unroll
    for (int i = 0; i < 2; ++i) {
      const int c = i * 256 + tid;
      const int row = c >> 3, kc = ((c & 7) ^ (row & 7)) << 3;
      const size_t dst = (size_t)(i * 256 + wave * 64) * 8;
      gload16(Bg + (size_t)(n0 + row) * K + kt + kc, lG + dst);
      gload16(Bu + (size_t)(n0 + row) * K + kt + kc, lU + dst);
    }
    __syncthreads();
    bf16x8 af[2][4], gf[2][2], uf[2][2];
#pragma unroll
    for (int kk = 0; kk < 2; ++kk) {
#pragma unroll
      for (int mi = 0; mi < 4; ++mi) {
        const int row = wr * 64 + mi * 16 + lr;
        af[kk][mi] = *(const bf16x8*)&lA[row * 64 + (((kk * 4 + lg) ^ (row & 7)) << 3)];
      }
#pragma unroll
      for (int ni = 0; ni < 2; ++ni) {
        const int row = wc * 32 + ni * 16 + lr;
        const int off = row * 64 + (((kk * 4 + lg) ^ (row & 7)) << 3);
        gf[kk][ni] = *(const bf16x8*)&lG[off];
        uf[kk][ni] = *(const bf16x8*)&lU[off];
      }
    }
#pragma unroll
    for (int kk = 0; kk < 2; ++kk)
#pragma unroll
      for (int mi = 0; mi < 4; ++mi)
#pragma unroll
        for (int ni = 0; ni < 2; ++ni) {
          ag[mi][ni] = __builtin_amdgcn_mfma_f32_16x16x32_bf16(
              af[kk][mi], gf[kk][ni], ag[mi][ni], 0, 0, 0);
          au[mi][ni] = __builtin_amdgcn_mfma_f32_16x16x32_bf16(
              af[kk][mi], uf[kk][ni], au[mi][ni], 0, 0, 0);
        }
  }
#pragma unroll
  for (int mi = 0; mi < 4; ++mi) {
#pragma unroll
    for (int ni = 0; ni < 2; ++ni) {
      const int col = n0 + wc * 32 + ni * 16 + lr;
#pragma unroll
      for (int j = 0; j < 4; ++j) {
        const int row = m0 + wr * 64 + mi * 16 + lg * 4 + j;
        const float g = ag[mi][ni][j];
        const float sg = g / (1.0f + __expf(-g));
        outT[(size_t)row * N + col] = f2bf(sg * au[mi][ni][j]);
      }
    }
  }
}

// ---------------------------------------------------------------------------
// Flash attention, swapped 32x32x16 structure (verified R4; pipelined R6;
// Vsh both-sides XOR R14; XCD K/V co-location R15).
// R17: p = exp2(s) via __builtin_amdgcn_exp2f (Q pre-scaled), no clamp.
// ---------------------------------------------------------------------------
__global__ __launch_bounds__(256) void attn_kernel(
    const u16* __restrict__ qkv, u16* __restrict__ ctx)
{
  constexpr int LD = 1536;
  const int orig = blockIdx.y * 8 + blockIdx.x;
  const int xcd = orig & 7, rnk = orig >> 3;
  const int bh = xcd * 8 + (rnk >> 3);
  const int qblk = rnk & 7;
  const int b = bh >> 3, h = bh & 7;
  const int tid = threadIdx.x, wave = tid >> 6, lane = tid & 63;
  const int l31 = lane & 31, half = lane >> 5;
  const size_t rowb = (size_t)b * 1024;
  const int q0 = qblk * 128 + wave * 32;

  __shared__ __align__(16) u16 Ksh[2][64 * 64];
  __shared__ __align__(16) u16 Vsh[2][64 * 72];   // [d][key], 144B rows
  __shared__ __align__(16) u16 PL[4][32 * 64];

  const u16* qrow = qkv + (rowb + q0 + l31) * LD + h * 64;
  bf16x8 qf[4];
#pragma unroll
  for (int c = 0; c < 4; ++c)
    qf[c] = *(const bf16x8*)(qrow + c * 16 + half * 8);

  const int krow0 = tid >> 3;
  const int kch0 = (tid & 7) ^ (krow0 & 7);
  const int vm = tid >> 3, vd0 = (tid & 7) * 8;
  const int vcol = (((vm >> 2) ^ (tid & 7)) << 4) + ((vm & 3) << 2);
  char* vbase0 = (char*)Vsh[0] + vcol;
  const u16* kg = qkv + rowb * LD + 512 + h * 64;
  const u16* vg = qkv + (rowb + 2 * vm) * LD + 1024 + h * 64 + vd0;

  f32x16 o0 = {}, o1 = {};
  float l_acc = 0.0f;

  gload16(kg + (size_t)(0 + krow0) * LD + kch0 * 8, Ksh[0] + wave * 512);
  gload16(kg + (size_t)(32 + krow0) * LD + kch0 * 8, Ksh[0] + 2048 + wave * 512);
  {
    u16x8 va = *(const u16x8*)vg;
    u16x8 vb = *(const u16x8*)(vg + LD);
#pragma unroll
    for (int j = 0; j < 8; ++j) {
      *(unsigned*)(vbase0 + (vd0 + j) * 144) =
          (unsigned)va[j] | ((unsigned)vb[j] << 16);
    }
  }
  __syncthreads();

  for (int t = 0; t < 16; ++t) {
    const int cur = t & 1, nxt = cur ^ 1;
    const int k0n = (t + 1) * 64;
    u16x8 va2, vb2;
    if (t < 15) {
      gload16(kg + (size_t)(k0n + krow0) * LD + kch0 * 8,
              Ksh[nxt] + wave * 512);
      gload16(kg + (size_t)(k0n + 32 + krow0) * LD + kch0 * 8,
              Ksh[nxt] + 2048 + wave * 512);
      va2 = *(const u16x8*)(vg + (size_t)k0n * LD);
      vb2 = *(const u16x8*)(vg + (size_t)k0n * LD + LD);
    }

    const char* kshb = (const char*)Ksh[cur];
    const char* vshb = (const char*)Vsh[cur];

    f32x16 s0 = {}, s1 = {};
#pragma unroll
    for (int c = 0; c < 4; ++c) {
      {
        const int row = l31;
        bf16x8 kf = *(const bf16x8*)(kshb + row * 128 +
                        ((((c << 1) | half) ^ (row & 7)) << 4));
        s0 = __builtin_amdgcn_mfma_f32_32x32x16_bf16(kf, qf[c], s0, 0, 0, 0);
      }
      {
        const int row = 32 + l31;
        bf16x8 kf = *(const bf16x8*)(kshb + row * 128 +
                        ((((c << 1) | half) ^ (row & 7)) << 4));
        s1 = __builtin_amdgcn_mfma_f32_32x32x16_bf16(kf, qf[c], s1, 0, 0, 0);
      }
    }

    char* plw = (char*)PL[wave];
#pragma unroll
    for (int blk = 0; blk < 2; ++blk) {
      const f32x16 sv = blk ? s1 : s0;
#pragma unroll
      for (int rg = 0; rg < 4; ++rg) {
        const float e0 = __builtin_amdgcn_exp2f(sv[rg * 4 + 0]);
        const float e1 = __builtin_amdgcn_exp2f(sv[rg * 4 + 1]);
        const float e2 = __builtin_amdgcn_exp2f(sv[rg * 4 + 2]);
        const float e3 = __builtin_amdgcn_exp2f(sv[rg * 4 + 3]);
        l_acc += (e0 + e1) + (e2 + e3);
        const unsigned lo = pk2(e0, e1);
        const unsigned hi = pk2(e2, e3);
        const int chunk = (rg + 4 * blk) ^ (l31 & 7);
        *(unsigned long long*)(plw + l31 * 128 + (chunk << 4) + half * 8) =
            (unsigned long long)lo | ((unsigned long long)hi << 32);
      }
    }

#pragma unroll
    for (int c = 0; c < 4; ++c) {
      bf16x8 pf = *(const bf16x8*)(plw + l31 * 128 +
                      ((((c << 1) | half) ^ (l31 & 7)) << 4));
      {
        const int row = l31;
        bf16x8 vf = *(const bf16x8*)(vshb + row * 144 +
                        ((((c << 1) | half) ^ (row >> 3)) << 4));
        o0 = __builtin_amdgcn_mfma_f32_32x32x16_bf16(pf, vf, o0, 0, 0, 0);
      }
      {
        const int row = 32 + l31;
        bf16x8 vf = *(const bf16x8*)(vshb + row * 144 +
                        ((((c << 1) | half) ^ (row >> 3)) << 4));
        o1 = __builtin_amdgcn_mfma_f32_32x32x16_bf16(pf, vf, o1, 0, 0, 0);
      }
    }

    if (t < 15) {
      char* vbn = (char*)Vsh[nxt] + vcol;
#pragma unroll
      for (int j = 0; j < 8; ++j) {
        *(unsigned*)(vbn + (vd0 + j) * 144) =
            (unsigned)va2[j] | ((unsigned)vb2[j] << 16);
      }
    }
    __syncthreads();
  }

  const float l_tot = l_acc + __shfl_xor(l_acc, 32);
  const float rl_all = 1.0f / l_tot;
#pragma unroll
  for (int r = 0; r < 16; ++r) {
    const int q_r = (r & 3) + 8 * (r >> 2) + 4 * half;
    const float rl = __shfl(rl_all, q_r);
    const size_t orow = (rowb + q0 + q_r) * 512 + h * 64 + l31;
    ctx[orow] = f2bf(o0[r] * rl);
    ctx[orow + 32] = f2bf(o1[r] * rl);
  }
}

// ---------------------------------------------------------------------------
extern "C" void kernel_launch(void* const* d_in, const int* in_sizes, int n_in,
                              void* d_out, int out_size, void* d_ws, size_t ws_size,
                              hipStream_t stream)
{
  (void)in_sizes; (void)n_in; (void)out_size; (void)ws_size;
  const float* src  = (const float*)d_in[0];
  const float* in_w = (const float*)d_in[1];
  const float* in_b = (const float*)d_in[2];
  const float* Wq   = (const float*)d_in[3];
  const float* Wk   = (const float*)d_in[4];
  const float* Wv   = (const float*)d_in[5];
  const float* Wo   = (const float*)d_in[6];
  const float* bq   = (const float*)d_in[7];
  const float* bk   = (const float*)d_in[8];
  const float* bv   = (const float*)d_in[9];
  const float* bo   = (const float*)d_in[10];
  const float* n1   = (const float*)d_in[11];
  const float* n2   = (const float*)d_in[12];
  const float* Wg   = (const float*)d_in[13];
  const float* Wu   = (const float*)d_in[14];
  const float* Wd   = (const float*)d_in[15];
  const float* gw   = (const float*)d_in[16];
  const float* gb   = (const float*)d_in[17];
  const float* fs   = (const float*)d_in[18];

  char* ws = (char*)d_ws;
  size_t off = 0;
  auto alloc = [&](size_t bytes) -> void* {
    void* p = ws + off;
    off += (bytes + 255) & ~(size_t)255;
    return p;
  };
  u16*   WqkvT = (u16*)alloc(6ULL * 1536 * 512 * 2);
  u16*   WoT   = (u16*)alloc(6ULL * 512 * 512 * 2);
  u16*   WgT   = (u16*)alloc(6ULL * 2048 * 512 * 2);
  u16*   WuT   = (u16*)alloc(6ULL * 2048 * 512 * 2);
  u16*   WdT   = (u16*)alloc(6ULL * 512 * 2048 * 2);
  float* bqkv  = (float*)alloc(6ULL * 1536 * 4);
  float* x     = (float*)alloc(8192ULL * 512 * 4);
  u16*   y     = (u16*)alloc(8192ULL * 512 * 2);   // bf16 residual y
  u16*   hbuf  = (u16*)alloc(8192ULL * 512 * 2);
  u16*   sA    = (u16*)alloc(8192ULL * 2048 * 2);
  u16*   sB    = (u16*)alloc(8192ULL * 2048 * 2);
  float* gp2   = (float*)alloc(8192 * 4);

  const dim3 tb(256);
  transpose_all_kernel<<<dim3(4096, 6), tb, 0, stream>>>(
      Wq, Wk, Wv, Wo, Wg, Wu, Wd, WqkvT, WoT, WgT, WuT, WdT);
  biaspack_kernel<<<6, tb, 0, stream>>>(bq, bk, bv, bqkv);
  adapter_kernel<<<dim3(2, 1024), tb, 0, stream>>>(src, in_w, in_b, x);

  for (int l = 0; l < 6; ++l) {
    rmsnorm_kernel<true, true><<<2048, tb, 0, stream>>>(
        x, n1 + l * 512, hbuf, nullptr, gw + l * 512, gp2);
    gemm_bt<0, 128><<<dim3(12, 64), tb, 0, stream>>>(
        hbuf, WqkvT + (size_t)l * 1536 * 512, bqkv + l * 1536,
        nullptr, nullptr, nullptr, sA, nullptr, nullptr, 0, 8192, 1536, 512);
    attn_kernel<<<dim3(8, 64), tb, 0, stream>>>(sA, sB);
    gemm_bt<1, 64><<<dim3(8, 64), tb, 0, stream>>>(
        sB, WoT + (size_t)l * 512 * 512, bo + l * 512,
        x, nullptr, nullptr, y, nullptr, nullptr, 0, 8192, 512, 512);
    rmsnorm_b16_kernel<<<2048, tb, 0, stream>>>(y, n2 + l * 512, hbuf);
    gemm_glu<<<dim3(32, 64), tb, 0, stream>>>(
        hbuf, WgT + (size_t)l * 2048 * 512, WuT + (size_t)l * 2048 * 512, sB);
    gemm_bt<4, 64><<<dim3(8, 64), tb, 0, stream>>>(
        sB, WdT + (size_t)l * 512 * 2048, nullptr,
        nullptr, y, x, nullptr, gp2, gb, l, 8192, 512, 2048);
  }
  rmsnorm_kernel<false, false><<<2048, tb, 0, stream>>>(
      x, fs, nullptr, (float*)d_out, nullptr, nullptr);
}

// Round 18
// 934.074 us; speedup vs baseline: 1.0408x; 1.0209x over previous
//
#include <hip/hip_runtime.h>

// ---------------------------------------------------------------------------
// TransformerEncoder on MI355X (gfx950).
// B=8 S=1024 IN=64 D=512 F=2048 H=8 HD=64 L=6. All inputs fp32, output fp32.
// R18: QKV GEMM -> BN=64 (3->6 blk/CU), unconfounded this time (R13 bundled
//      it with attn setprio which hurt the barrier-locked attn regime).
// ---------------------------------------------------------------------------

typedef unsigned short u16;
typedef __attribute__((ext_vector_type(8))) __bf16 bf16x8;
typedef __attribute__((ext_vector_type(2))) __bf16 bf16x2;
typedef __attribute__((ext_vector_type(4))) float f32x4;
typedef __attribute__((ext_vector_type(16))) float f32x16;
typedef __attribute__((ext_vector_type(8))) unsigned short u16x8;

#define DEV __device__ __forceinline__

DEV u16 f2bf(float f) {               // native RNE cast (HW v_cvt)
  __bf16 h = (__bf16)f;
  return __builtin_bit_cast(u16, h);
}
DEV float bf2f(u16 h) { return __builtin_bit_cast(float, ((unsigned)h) << 16); }
DEV unsigned pk2(float a, float b) {  // pack 2 floats -> 2 bf16 (cvt_pk)
  bf16x2 v; v[0] = (__bf16)a; v[1] = (__bf16)b;
  return __builtin_bit_cast(unsigned, v);
}

DEV void gload16(const void* g, void* l) {
  __builtin_amdgcn_global_load_lds(
      (__attribute__((address_space(1))) void*)g,
      (__attribute__((address_space(3))) void*)l, 16, 0, 0);
}

// XCD chunked swizzle: XCD owns contiguous by-strip, all bx.
DEV void xcd_map(int& bx, int& by) {
  const int nx = gridDim.x, ny = gridDim.y;
  const int orig = by * nx + bx;
  const int cpx = (nx * ny) >> 3;
  const int swz = (orig & 7) * cpx + (orig >> 3);
  by = swz / nx; bx = swz - by * nx;
}

// ---------------------------------------------------------------------------
// Batched weight transpose fp32 [K][N] -> bf16 [N][K], all weights, all layers.
// ---------------------------------------------------------------------------
__global__ __launch_bounds__(256) void transpose_all_kernel(
    const float* __restrict__ Wq, const float* __restrict__ Wk,
    const float* __restrict__ Wv, const float* __restrict__ Wo,
    const float* __restrict__ Wg, const float* __restrict__ Wu,
    const float* __restrict__ Wd,
    u16* __restrict__ WqkvT, u16* __restrict__ WoT, u16* __restrict__ WgT,
    u16* __restrict__ WuT, u16* __restrict__ WdT)
{
  const int l = blockIdx.y;
  const int idx = blockIdx.x;
  const float* src; u16* dst; int N, bx, by;
  if (idx < 1024) {
    const int w = idx >> 8, t = idx & 255;
    bx = t & 15; by = t >> 4; N = 512;
    const size_t lo = (size_t)l * 262144;
    if (w == 0)      { src = Wq + lo; dst = WqkvT + (size_t)l * 786432; }
    else if (w == 1) { src = Wk + lo; dst = WqkvT + (size_t)l * 786432 + 262144; }
    else if (w == 2) { src = Wv + lo; dst = WqkvT + (size_t)l * 786432 + 524288; }
    else             { src = Wo + lo; dst = WoT + lo; }
  } else if (idx < 2048) {
    const int t = idx - 1024; bx = t & 63; by = t >> 6; N = 2048;
    src = Wg + (size_t)l * 1048576; dst = WgT + (size_t)l * 1048576;
  } else if (idx < 3072) {
    const int t = idx - 2048; bx = t & 63; by = t >> 6; N = 2048;
    src = Wu + (size_t)l * 1048576; dst = WuT + (size_t)l * 1048576;
  } else {
    const int t = idx - 3072; bx = t & 15; by = t >> 4; N = 512;
    src = Wd + (size_t)l * 1048576; dst = WdT + (size_t)l * 1048576;
  }
  const int K = (idx >= 3072) ? 2048 : 512;
  __shared__ float tl[32][33];
  const int n0 = bx * 32, k0 = by * 32;
  const int tx = threadIdx.x & 31, ty = threadIdx.x >> 5;
#pragma unroll
  for (int i = 0; i < 4; ++i)
    tl[ty + i * 8][tx] = src[(size_t)(k0 + ty + i * 8) * N + n0 + tx];
  __syncthreads();
#pragma unroll
  for (int i = 0; i < 4; ++i)
    dst[(size_t)(n0 + ty + i * 8) * K + k0 + tx] = f2bf(tl[tx][ty + i * 8]);
}

// pack bq|bk|bv into [L][1536]
__global__ void biaspack_kernel(const float* __restrict__ bq,
                                const float* __restrict__ bk,
                                const float* __restrict__ bv,
                                float* __restrict__ out)
{
  const int l = blockIdx.x;
  for (int c = threadIdx.x; c < 1536; c += 256) {
    float v = (c < 512) ? bq[l * 512 + c]
            : (c < 1024) ? bk[l * 512 + c - 512]
                         : bv[l * 512 + c - 1024];
    out[l * 1536 + c] = v;
  }
}

// ---------------------------------------------------------------------------
// Input adapter: x = src @ in_w + in_b + sinusoidal_pe   (fp32, [8192][512])
// ---------------------------------------------------------------------------
__global__ __launch_bounds__(256) void adapter_kernel(
    const float* __restrict__ src, const float* __restrict__ w,
    const float* __restrict__ bias, float* __restrict__ x)
{
  __shared__ float srow[8][64];
  const int m0 = blockIdx.y * 8;
  const int n = blockIdx.x * 256 + threadIdx.x;
  for (int i = threadIdx.x; i < 512; i += 256)
    srow[i >> 6][i & 63] = src[(size_t)m0 * 64 + i];
  __syncthreads();
  float acc[8];
#pragma unroll
  for (int r = 0; r < 8; ++r) acc[r] = bias[n];
  for (int k = 0; k < 64; ++k) {
    const float wv = w[(size_t)k * 512 + n];
#pragma unroll
    for (int r = 0; r < 8; ++r) acc[r] = fmaf(srow[r][k], wv, acc[r]);
  }
  const int i2 = n & ~1;
  const float freq = expf((float)i2 * (-9.210340371976184f / 512.0f));
#pragma unroll
  for (int r = 0; r < 8; ++r) {
    const int pos = (m0 + r) & 1023;
    const float ang = (float)pos * freq;
    acc[r] += (n & 1) ? cosf(ang) : sinf(ang);
    x[(size_t)(m0 + r) * 512 + n] = acc[r];
  }
}

// ---------------------------------------------------------------------------
// RMSNorm fp32-in (one wave per 512-row). GATE: emit per-wave gate partials.
// ---------------------------------------------------------------------------
template <bool BF16OUT, bool GATE>
__global__ __launch_bounds__(256) void rmsnorm_kernel(
    const float* __restrict__ x, const float* __restrict__ scale,
    u16* __restrict__ outb, float* __restrict__ outf,
    const float* __restrict__ gw, float* __restrict__ gp2)
{
  const int wave = threadIdx.x >> 6, lane = threadIdx.x & 63;
  const size_t row = (size_t)blockIdx.x * 4 + wave;
  const f32x4* xr = (const f32x4*)(x + row * 512);
  f32x4 a = xr[lane * 2], c = xr[lane * 2 + 1];
  float ss = a[0]*a[0] + a[1]*a[1] + a[2]*a[2] + a[3]*a[3]
           + c[0]*c[0] + c[1]*c[1] + c[2]*c[2] + c[3]*c[3];
  float dv = 0.0f;
  if (GATE) {
    const f32x4* gr = (const f32x4*)gw;
    f32x4 g1 = gr[lane * 2], g2 = gr[lane * 2 + 1];
    dv = a[0]*g1[0] + a[1]*g1[1] + a[2]*g1[2] + a[3]*g1[3]
       + c[0]*g2[0] + c[1]*g2[1] + c[2]*g2[2] + c[3]*g2[3];
  }
#pragma unroll
  for (int d = 1; d < 64; d <<= 1) {
    ss += __shfl_xor(ss, d);
    if (GATE) dv += __shfl_xor(dv, d);
  }
  if (GATE && lane == 0) gp2[blockIdx.x * 4 + wave] = dv;
  const float r = rsqrtf(ss * (1.0f / 512.0f) + 1e-5f);
  const f32x4* sr = (const f32x4*)scale;
  f32x4 s1 = sr[lane * 2], s2 = sr[lane * 2 + 1];
  if (BF16OUT) {
    u16x8 ov;
    ov[0] = f2bf(a[0] * s1[0] * r); ov[1] = f2bf(a[1] * s1[1] * r);
    ov[2] = f2bf(a[2] * s1[2] * r); ov[3] = f2bf(a[3] * s1[3] * r);
    ov[4] = f2bf(c[0] * s2[0] * r); ov[5] = f2bf(c[1] * s2[1] * r);
    ov[6] = f2bf(c[2] * s2[2] * r); ov[7] = f2bf(c[3] * s2[3] * r);
    *(u16x8*)(outb + row * 512 + lane * 8) = ov;
  } else {
    f32x4 o1, o2;
    o1[0] = a[0]*s1[0]*r; o1[1] = a[1]*s1[1]*r; o1[2] = a[2]*s1[2]*r; o1[3] = a[3]*s1[3]*r;
    o2[0] = c[0]*s2[0]*r; o2[1] = c[1]*s2[1]*r; o2[2] = c[2]*s2[2]*r; o2[3] = c[3]*s2[3]*r;
    f32x4* orow = (f32x4*)(outf + row * 512);
    orow[lane * 2] = o1; orow[lane * 2 + 1] = o2;
  }
}

// RMSNorm bf16-in -> bf16 out (for the y residual stream)
__global__ __launch_bounds__(256) void rmsnorm_b16_kernel(
    const u16* __restrict__ y, const float* __restrict__ scale,
    u16* __restrict__ outb)
{
  const int wave = threadIdx.x >> 6, lane = threadIdx.x & 63;
  const size_t row = (size_t)blockIdx.x * 4 + wave;
  const u16x8 v8 = *(const u16x8*)(y + row * 512 + lane * 8);
  float f[8];
#pragma unroll
  for (int j = 0; j < 8; ++j) f[j] = bf2f(v8[j]);
  float ss = 0.0f;
#pragma unroll
  for (int j = 0; j < 8; ++j) ss += f[j] * f[j];
#pragma unroll
  for (int d = 1; d < 64; d <<= 1) ss += __shfl_xor(ss, d);
  const float r = rsqrtf(ss * (1.0f / 512.0f) + 1e-5f);
  const f32x4* sr = (const f32x4*)scale;
  f32x4 s1 = sr[lane * 2], s2 = sr[lane * 2 + 1];
  u16x8 ov;
  ov[0] = f2bf(f[0] * s1[0] * r); ov[1] = f2bf(f[1] * s1[1] * r);
  ov[2] = f2bf(f[2] * s1[2] * r); ov[3] = f2bf(f[3] * s1[3] * r);
  ov[4] = f2bf(f[4] * s2[0] * r); ov[5] = f2bf(f[5] * s2[1] * r);
  ov[6] = f2bf(f[6] * s2[2] * r); ov[7] = f2bf(f[7] * s2[3] * r);
  *(u16x8*)(outb + row * 512 + lane * 8) = ov;
}

// ---------------------------------------------------------------------------
// GEMM (R7 single-buffer): BM=128, BK=64, BN in {64,128}; 4 waves.
// MODE 0: +bias, cols<512 * log2e/8 -> bf16 out              (QKV)
// MODE 1: +bias + resf(x,f32) -> bf16 out                    (attn out proj)
// MODE 4: gate-reduce + resb(y,bf16) -> f32 out x            (FFN down proj)
// ---------------------------------------------------------------------------
template <int MODE, int BN>
__global__ __launch_bounds__(256) void gemm_bt(
    const u16* __restrict__ A, const u16* __restrict__ Bt,
    const float* __restrict__ bias, const float* __restrict__ resf,
    const u16* __restrict__ resb, float* __restrict__ outf,
    u16* __restrict__ outb, const float* __restrict__ gatep,
    const float* __restrict__ gbias, int layer, int M, int N, int K)
{
  constexpr int NI = BN / 32;
  __shared__ __align__(16) u16 lA[128 * 64];
  __shared__ __align__(16) u16 lB[BN * 64];
  const int tid = threadIdx.x;
  const int wave = tid >> 6, lane = tid & 63;
  const int lr = lane & 15, lg = lane >> 4;
  int bx = blockIdx.x, by = blockIdx.y;
  xcd_map(bx, by);
  const int m0 = by << 7, n0 = bx * BN;
  const int wr = wave >> 1, wc = wave & 1;
  if (MODE == 4) {
    __shared__ float red[64];
    __shared__ float gfl;
    const float* g4 = gatep + (size_t)(m0 >> 10) * 256;
    float v = (tid < 256) ? g4[tid] : 0.0f;
#pragma unroll
    for (int d = 1; d < 64; d <<= 1) v += __shfl_xor(v, d);
    if (lane == 0) red[wave] = v;
    __syncthreads();
    if (tid == 0) {
      const float s = red[0] + red[1] + red[2] + red[3];
      gfl = (s / 1024.0f + gbias[layer] > 0.0f) ? 1.0f : 0.0f;
    }
    __syncthreads();
    if (gfl == 0.0f) return;
  }
  f32x4 acc[4][NI] = {};
  for (int kt = 0; kt < K; kt += 64) {
    __syncthreads();
#pragma unroll
    for (int i = 0; i < 4; ++i) {
      const int c = i * 256 + tid;
      const int row = c >> 3, kc = ((c & 7) ^ (row & 7)) << 3;
      gload16(A + (size_t)(m0 + row) * K + kt + kc,
              lA + (size_t)(i * 256 + wave * 64) * 8);
    }
#pragma unroll
    for (int i = 0; i < BN / 32; ++i) {
      const int c = i * 256 + tid;
      const int row = c >> 3, kc = ((c & 7) ^ (row & 7)) << 3;
      gload16(Bt + (size_t)(n0 + row) * K + kt + kc,
              lB + (size_t)(i * 256 + wave * 64) * 8);
    }
    __syncthreads();
    bf16x8 af[2][4], bfr[2][NI];
#pragma unroll
    for (int kk = 0; kk < 2; ++kk) {
#pragma unroll
      for (int mi = 0; mi < 4; ++mi) {
        const int row = wr * 64 + mi * 16 + lr;
        af[kk][mi] = *(const bf16x8*)&lA[row * 64 + (((kk * 4 + lg) ^ (row & 7)) << 3)];
      }
#pragma unroll
      for (int ni = 0; ni < NI; ++ni) {
        const int row = wc * (BN / 2) + ni * 16 + lr;
        bfr[kk][ni] = *(const bf16x8*)&lB[row * 64 + (((kk * 4 + lg) ^ (row & 7)) << 3)];
      }
    }
#pragma unroll
    for (int kk = 0; kk < 2; ++kk)
#pragma unroll
      for (int mi = 0; mi < 4; ++mi)
#pragma unroll
        for (int ni = 0; ni < NI; ++ni)
          acc[mi][ni] = __builtin_amdgcn_mfma_f32_16x16x32_bf16(
              af[kk][mi], bfr[kk][ni], acc[mi][ni], 0, 0, 0);
  }
#pragma unroll
  for (int mi = 0; mi < 4; ++mi) {
#pragma unroll
    for (int ni = 0; ni < NI; ++ni) {
      const int col = n0 + wc * (BN / 2) + ni * 16 + lr;
      const float bs = (MODE == 0 || MODE == 1) ? bias[col] : 0.0f;
#pragma unroll
      for (int j = 0; j < 4; ++j) {
        const int row = m0 + wr * 64 + mi * 16 + lg * 4 + j;
        const size_t idx = (size_t)row * N + col;
        float v = acc[mi][ni][j] + bs;
        if (MODE == 0) {
          // Q pre-scale: 1/sqrt(HD) * log2(e)  (softmax uses exp2 directly)
          if (col < 512) v *= 0.18033688011112042f;
          outb[idx] = f2bf(v);
        } else if (MODE == 1) {
          outb[idx] = f2bf(v + resf[idx]);     // y (bf16) = x + ctx@Wo
        } else {                               // MODE 4
          outf[idx] = v + bf2f(resb[idx]);     // x (f32) = ffn + y
        }
      }
    }
  }
}

// ---------------------------------------------------------------------------
// Fused SwiGLU FFN front (R10 form): T = silu(A@WgT^T) * (A@WuT^T), bf16.
// M=8192, N=2048, K=512. BM=128, BN=64, BK=64; 2-phase; 2D XCD tiling.
// ---------------------------------------------------------------------------
__global__ __launch_bounds__(256) void gemm_glu(
    const u16* __restrict__ A, const u16* __restrict__ Bg,
    const u16* __restrict__ Bu, u16* __restrict__ outT)
{
  constexpr int K = 512, N = 2048;
  __shared__ __align__(16) u16 lA[128 * 64];
  __shared__ __align__(16) u16 lG[64 * 64];
  __shared__ __align__(16) u16 lU[64 * 64];
  const int tid = threadIdx.x;
  const int wave = tid >> 6, lane = tid & 63;
  const int lr = lane & 15, lg = lane >> 4;
  const int orig = blockIdx.y * gridDim.x + blockIdx.x;
  const int xcd = orig & 7, rnk = orig >> 3;
  const int bx = (xcd & 1) * 16 + (rnk >> 4);
  const int by = (xcd >> 1) * 16 + (rnk & 15);
  const int m0 = by << 7, n0 = bx << 6;
  const int wr = wave >> 1, wc = wave & 1;
  f32x4 ag[4][2] = {}, au[4][2] = {};
  for (int kt = 0; kt < K; kt += 64) {
    __syncthreads();
#pragma unroll
    for (int i = 0; i < 4; ++i) {
      const int c = i * 256 + tid;
      const int row = c >> 3, kc = ((c & 7) ^ (row & 7)) << 3;
      gload16(A + (size_t)(m0 + row) * K + kt + kc,
              lA + (size_t)(i * 256 + wave * 64) * 8);
    }
#pragma unroll
    for (int i = 0; i < 2; ++i) {
      const int c = i * 256 + tid;
      const int row = c >> 3, kc = ((c & 7) ^ (row & 7)) << 3;
      const size_t dst = (size_t)(i * 256 + wave * 64) * 8;
      gload16(Bg + (size_t)(n0 + row) * K + kt + kc, lG + dst);
      gload16(Bu + (size_t)(n0 + row) * K + kt + kc, lU + dst);
    }
    __syncthreads();
    bf16x8 af[2][4], gf[2][2], uf[2][2];
#pragma unroll
    for (int kk = 0; kk < 2; ++kk) {
#pragma unroll
      for (int mi = 0; mi < 4; ++mi) {
        const int row = wr * 64 + mi * 16 + lr;
        af[kk][mi] = *(const bf16x8*)&lA[row * 64 + (((kk * 4 + lg) ^ (row & 7)) << 3)];
      }
#pragma unroll
      for (int ni = 0; ni < 2; ++ni) {
        const int row = wc * 32 + ni * 16 + lr;
        const int off = row * 64 + (((kk * 4 + lg) ^ (row & 7)) << 3);
        gf[kk][ni] = *(const bf16x8*)&lG[off];
        uf[kk][ni] = *(const bf16x8*)&lU[off];
      }
    }
#pragma unroll
    for (int kk = 0; kk < 2; ++kk)
#pragma unroll
      for (int mi = 0; mi < 4; ++mi)
#pragma unroll
        for (int ni = 0; ni < 2; ++ni) {
          ag[mi][ni] = __builtin_amdgcn_mfma_f32_16x16x32_bf16(
              af[kk][mi], gf[kk][ni], ag[mi][ni], 0, 0, 0);
          au[mi][ni] = __builtin_amdgcn_mfma_f32_16x16x32_bf16(
              af[kk][mi], uf[kk][ni], au[mi][ni], 0, 0, 0);
        }
  }
#pragma unroll
  for (int mi = 0; mi < 4; ++mi) {
#pragma unroll
    for (int ni = 0; ni < 2; ++ni) {
      const int col = n0 + wc * 32 + ni * 16 + lr;
#pragma unroll
      for (int j = 0; j < 4; ++j) {
        const int row = m0 + wr * 64 + mi * 16 + lg * 4 + j;
        const float g = ag[mi][ni][j];
        const float sg = g / (1.0f + __expf(-g));
        outT[(size_t)row * N + col] = f2bf(sg * au[mi][ni][j]);
      }
    }
  }
}

// ---------------------------------------------------------------------------
// Flash attention, swapped 32x32x16 structure (verified R4; pipelined R6;
// Vsh both-sides XOR R14; XCD K/V co-location R15; exp2 softmax R17).
// ---------------------------------------------------------------------------
__global__ __launch_bounds__(256) void attn_kernel(
    const u16* __restrict__ qkv, u16* __restrict__ ctx)
{
  constexpr int LD = 1536;
  const int orig = blockIdx.y * 8 + blockIdx.x;
  const int xcd = orig & 7, rnk = orig >> 3;
  const int bh = xcd * 8 + (rnk >> 3);
  const int qblk = rnk & 7;
  const int b = bh >> 3, h = bh & 7;
  const int tid = threadIdx.x, wave = tid >> 6, lane = tid & 63;
  const int l31 = lane & 31, half = lane >> 5;
  const size_t rowb = (size_t)b * 1024;
  const int q0 = qblk * 128 + wave * 32;

  __shared__ __align__(16) u16 Ksh[2][64 * 64];
  __shared__ __align__(16) u16 Vsh[2][64 * 72];   // [d][key], 144B rows
  __shared__ __align__(16) u16 PL[4][32 * 64];

  const u16* qrow = qkv + (rowb + q0 + l31) * LD + h * 64;
  bf16x8 qf[4];
#pragma unroll
  for (int c = 0; c < 4; ++c)
    qf[c] = *(const bf16x8*)(qrow + c * 16 + half * 8);

  const int krow0 = tid >> 3;
  const int kch0 = (tid & 7) ^ (krow0 & 7);
  const int vm = tid >> 3, vd0 = (tid & 7) * 8;
  const int vcol = (((vm >> 2) ^ (tid & 7)) << 4) + ((vm & 3) << 2);
  char* vbase0 = (char*)Vsh[0] + vcol;
  const u16* kg = qkv + rowb * LD + 512 + h * 64;
  const u16* vg = qkv + (rowb + 2 * vm) * LD + 1024 + h * 64 + vd0;

  f32x16 o0 = {}, o1 = {};
  float l_acc = 0.0f;

  gload16(kg + (size_t)(0 + krow0) * LD + kch0 * 8, Ksh[0] + wave * 512);
  gload16(kg + (size_t)(32 + krow0) * LD + kch0 * 8, Ksh[0] + 2048 + wave * 512);
  {
    u16x8 va = *(const u16x8*)vg;
    u16x8 vb = *(const u16x8*)(vg + LD);
#pragma unroll
    for (int j = 0; j < 8; ++j) {
      *(unsigned*)(vbase0 + (vd0 + j) * 144) =
          (unsigned)va[j] | ((unsigned)vb[j] << 16);
    }
  }
  __syncthreads();

  for (int t = 0; t < 16; ++t) {
    const int cur = t & 1, nxt = cur ^ 1;
    const int k0n = (t + 1) * 64;
    u16x8 va2, vb2;
    if (t < 15) {
      gload16(kg + (size_t)(k0n + krow0) * LD + kch0 * 8,
              Ksh[nxt] + wave * 512);
      gload16(kg + (size_t)(k0n + 32 + krow0) * LD + kch0 * 8,
              Ksh[nxt] + 2048 + wave * 512);
      va2 = *(const u16x8*)(vg + (size_t)k0n * LD);
      vb2 = *(const u16x8*)(vg + (size_t)k0n * LD + LD);
    }

    const char* kshb = (const char*)Ksh[cur];
    const char* vshb = (const char*)Vsh[cur];

    f32x16 s0 = {}, s1 = {};
#pragma unroll
    for (int c = 0; c < 4; ++c) {
      {
        const int row = l31;
        bf16x8 kf = *(const bf16x8*)(kshb + row * 128 +
                        ((((c << 1) | half) ^ (row & 7)) << 4));
        s0 = __builtin_amdgcn_mfma_f32_32x32x16_bf16(kf, qf[c], s0, 0, 0, 0);
      }
      {
        const int row = 32 + l31;
        bf16x8 kf = *(const bf16x8*)(kshb + row * 128 +
                        ((((c << 1) | half) ^ (row & 7)) << 4));
        s1 = __builtin_amdgcn_mfma_f32_32x32x16_bf16(kf, qf[c], s1, 0, 0, 0);
      }
    }

    char* plw = (char*)PL[wave];
#pragma unroll
    for (int blk = 0; blk < 2; ++blk) {
      const f32x16 sv = blk ? s1 : s0;
#pragma unroll
      for (int rg = 0; rg < 4; ++rg) {
        const float e0 = __builtin_amdgcn_exp2f(sv[rg * 4 + 0]);
        const float e1 = __builtin_amdgcn_exp2f(sv[rg * 4 + 1]);
        const float e2 = __builtin_amdgcn_exp2f(sv[rg * 4 + 2]);
        const float e3 = __builtin_amdgcn_exp2f(sv[rg * 4 + 3]);
        l_acc += (e0 + e1) + (e2 + e3);
        const unsigned lo = pk2(e0, e1);
        const unsigned hi = pk2(e2, e3);
        const int chunk = (rg + 4 * blk) ^ (l31 & 7);
        *(unsigned long long*)(plw + l31 * 128 + (chunk << 4) + half * 8) =
            (unsigned long long)lo | ((unsigned long long)hi << 32);
      }
    }

#pragma unroll
    for (int c = 0; c < 4; ++c) {
      bf16x8 pf = *(const bf16x8*)(plw + l31 * 128 +
                      ((((c << 1) | half) ^ (l31 & 7)) << 4));
      {
        const int row = l31;
        bf16x8 vf = *(const bf16x8*)(vshb + row * 144 +
                        ((((c << 1) | half) ^ (row >> 3)) << 4));
        o0 = __builtin_amdgcn_mfma_f32_32x32x16_bf16(pf, vf, o0, 0, 0, 0);
      }
      {
        const int row = 32 + l31;
        bf16x8 vf = *(const bf16x8*)(vshb + row * 144 +
                        ((((c << 1) | half) ^ (row >> 3)) << 4));
        o1 = __builtin_amdgcn_mfma_f32_32x32x16_bf16(pf, vf, o1, 0, 0, 0);
      }
    }

    if (t < 15) {
      char* vbn = (char*)Vsh[nxt] + vcol;
#pragma unroll
      for (int j = 0; j < 8; ++j) {
        *(unsigned*)(vbn + (vd0 + j) * 144) =
            (unsigned)va2[j] | ((unsigned)vb2[j] << 16);
      }
    }
    __syncthreads();
  }

  const float l_tot = l_acc + __shfl_xor(l_acc, 32);
  const float rl_all = 1.0f / l_tot;
#pragma unroll
  for (int r = 0; r < 16; ++r) {
    const int q_r = (r & 3) + 8 * (r >> 2) + 4 * half;
    const float rl = __shfl(rl_all, q_r);
    const size_t orow = (rowb + q0 + q_r) * 512 + h * 64 + l31;
    ctx[orow] = f2bf(o0[r] * rl);
    ctx[orow + 32] = f2bf(o1[r] * rl);
  }
}

// ---------------------------------------------------------------------------
extern "C" void kernel_launch(void* const* d_in, const int* in_sizes, int n_in,
                              void* d_out, int out_size, void* d_ws, size_t ws_size,
                              hipStream_t stream)
{
  (void)in_sizes; (void)n_in; (void)out_size; (void)ws_size;
  const float* src  = (const float*)d_in[0];
  const float* in_w = (const float*)d_in[1];
  const float* in_b = (const float*)d_in[2];
  const float* Wq   = (const float*)d_in[3];
  const float* Wk   = (const float*)d_in[4];
  const float* Wv   = (const float*)d_in[5];
  const float* Wo   = (const float*)d_in[6];
  const float* bq   = (const float*)d_in[7];
  const float* bk   = (const float*)d_in[8];
  const float* bv   = (const float*)d_in[9];
  const float* bo   = (const float*)d_in[10];
  const float* n1   = (const float*)d_in[11];
  const float* n2   = (const float*)d_in[12];
  const float* Wg   = (const float*)d_in[13];
  const float* Wu   = (const float*)d_in[14];
  const float* Wd   = (const float*)d_in[15];
  const float* gw   = (const float*)d_in[16];
  const float* gb   = (const float*)d_in[17];
  const float* fs   = (const float*)d_in[18];

  char* ws = (char*)d_ws;
  size_t off = 0;
  auto alloc = [&](size_t bytes) -> void* {
    void* p = ws + off;
    off += (bytes + 255) & ~(size_t)255;
    return p;
  };
  u16*   WqkvT = (u16*)alloc(6ULL * 1536 * 512 * 2);
  u16*   WoT   = (u16*)alloc(6ULL * 512 * 512 * 2);
  u16*   WgT   = (u16*)alloc(6ULL * 2048 * 512 * 2);
  u16*   WuT   = (u16*)alloc(6ULL * 2048 * 512 * 2);
  u16*   WdT   = (u16*)alloc(6ULL * 512 * 2048 * 2);
  float* bqkv  = (float*)alloc(6ULL * 1536 * 4);
  float* x     = (float*)alloc(8192ULL * 512 * 4);
  u16*   y     = (u16*)alloc(8192ULL * 512 * 2);   // bf16 residual y
  u16*   hbuf  = (u16*)alloc(8192ULL * 512 * 2);
  u16*   sA    = (u16*)alloc(8192ULL * 2048 * 2);
  u16*   sB    = (u16*)alloc(8192ULL * 2048 * 2);
  float* gp2   = (float*)alloc(8192 * 4);

  const dim3 tb(256);
  transpose_all_kernel<<<dim3(4096, 6), tb, 0, stream>>>(
      Wq, Wk, Wv, Wo, Wg, Wu, Wd, WqkvT, WoT, WgT, WuT, WdT);
  biaspack_kernel<<<6, tb, 0, stream>>>(bq, bk, bv, bqkv);
  adapter_kernel<<<dim3(2, 1024), tb, 0, stream>>>(src, in_w, in_b, x);

  for (int l = 0; l < 6; ++l) {
    rmsnorm_kernel<true, true><<<2048, tb, 0, stream>>>(
        x, n1 + l * 512, hbuf, nullptr, gw + l * 512, gp2);
    gemm_bt<0, 64><<<dim3(24, 64), tb, 0, stream>>>(
        hbuf, WqkvT + (size_t)l * 1536 * 512, bqkv + l * 1536,
        nullptr, nullptr, nullptr, sA, nullptr, nullptr, 0, 8192, 1536, 512);
    attn_kernel<<<dim3(8, 64), tb, 0, stream>>>(sA, sB);
    gemm_bt<1, 64><<<dim3(8, 64), tb, 0, stream>>>(
        sB, WoT + (size_t)l * 512 * 512, bo + l * 512,
        x, nullptr, nullptr, y, nullptr, nullptr, 0, 8192, 512, 512);
    rmsnorm_b16_kernel<<<2048, tb, 0, stream>>>(y, n2 + l * 512, hbuf);
    gemm_glu<<<dim3(32, 64), tb, 0, stream>>>(
        hbuf, WgT + (size_t)l * 2048 * 512, WuT + (size_t)l * 2048 * 512, sB);
    gemm_bt<4, 64><<<dim3(8, 64), tb, 0, stream>>>(
        sB, WdT + (size_t)l * 512 * 2048, nullptr,
        nullptr, y, x, nullptr, gp2, gb, l, 8192, 512, 2048);
  }
  rmsnorm_kernel<false, false><<<2048, tb, 0, stream>>>(
      x, fs, nullptr, (float*)d_out, nullptr, nullptr);
}